// Round 10
// baseline (710.471 us; speedup 1.0000x reference)
//
#include <hip/hip_runtime.h>
#include <hip/hip_bf16.h>
#include <math.h>

#define Nn 8192
#define Dd 256
#define Uu 128
#define MI 16
#define JS 2
#define JRANGE (Nn / JS)          // 4096
#define NWIN (JRANGE / 64)        // 64 windows per block
#define NMASK (Nn / 64)           // 128 mask words per row
#define ZTOT4 ((Nn * Uu + Nn) / 4)

typedef __attribute__((ext_vector_type(4))) float f32x4;
typedef __attribute__((ext_vector_type(8))) short s16x8;
typedef __attribute__((ext_vector_type(4))) short s16x4;

#define MFMA_K32(a, b, c) __builtin_amdgcn_mfma_f32_16x16x32_bf16((a), (b), (c), 0, 0, 0)

__device__ __forceinline__ short f2bf(float f){
  unsigned int u = __float_as_uint(f);
  u += 0x7fffu + ((u >> 16) & 1u);           // RNE
  return (short)(u >> 16);
}

// LDS-only barrier (no vmcnt drain). R9 showed it's perf-neutral vs __syncthreads,
// but it is still the correct minimal barrier for the Pt ping-pong tile.
__device__ __forceinline__ void lds_barrier(){
  asm volatile("s_waitcnt lgkmcnt(0)\n\ts_barrier" ::: "memory");
}

__device__ __forceinline__ float waveSum(float v){
  #pragma unroll
  for (int off = 32; off >= 1; off >>= 1) v += __shfl_xor(v, off);
  return v;
}

// Pack adj (0/1 int32, 268 MB) into 64-bit window masks (8 MB), diagonal cleared.
// Removes the cold-HBM stream from k_attn's in-order vmcnt queue (the R6-R9 stall).
__global__ __launch_bounds__(256) void k_pack(const int* __restrict__ adj,
                                              unsigned long long* __restrict__ amask){
  const int lane = threadIdx.x & 63;
  const int wv   = blockIdx.x * 4 + (threadIdx.x >> 6);
  const int strd = gridDim.x * 4;
  for (int m = wv; m < Nn * NMASK; m += 2 * strd){
    const int m2   = m + strd;
    const int row  = m >> 7,  row2 = m2 >> 7;
    const int jc   = (m  & 127) * 64 + lane;
    const int jc2  = (m2 & 127) * 64 + lane;
    int a  = adj[(size_t)row  * Nn + jc ];
    int a2 = adj[(size_t)row2 * Nn + jc2];
    if (jc  == row ) a  = 0;               // clear diagonal (ref: dist_ii==0 -> masked)
    if (jc2 == row2) a2 = 0;
    const unsigned long long b  = __ballot(a  != 0);
    const unsigned long long b2 = __ballot(a2 != 0);
    if (lane == 0){ amask[m] = b; amask[m2] = b2; }
  }
}

// x = expmap0(features @ kernel) -> xh (bf16 [N][U]), x2 = tanh(|z|)^2; zeroes Oacc+lac
__global__ __launch_bounds__(128) void k_prep(const float* __restrict__ feat,
                                              const float* __restrict__ kern,
                                              short* __restrict__ xh,
                                              float* __restrict__ x2,
                                              float4* __restrict__ zreg){
  const int t = threadIdx.x;                  // == u
  const int n0 = blockIdx.x * 16;
  __shared__ float fS[16][Dd];
  __shared__ float red[2][16];
  {
    const float4 z4 = {0.f, 0.f, 0.f, 0.f};
    for (int i = blockIdx.x * 128 + t; i < ZTOT4; i += 512 * 128) zreg[i] = z4;
  }
  {
    const f32x4* fg = (const f32x4*)(feat + (size_t)n0 * Dd);
    f32x4* fd = (f32x4*)fS;
    #pragma unroll
    for (int c = 0; c < 8; ++c) fd[c * 128 + t] = fg[c * 128 + t];
  }
  __syncthreads();
  float zz[16];
  #pragma unroll
  for (int r = 0; r < 16; ++r) zz[r] = 0.f;
  for (int dq = 0; dq < 64; ++dq){
    const int d = dq * 4;
    const float k0 = kern[(size_t)(d + 0) * Uu + t];
    const float k1 = kern[(size_t)(d + 1) * Uu + t];
    const float k2 = kern[(size_t)(d + 2) * Uu + t];
    const float k3 = kern[(size_t)(d + 3) * Uu + t];
    #pragma unroll
    for (int r = 0; r < 16; ++r){
      const f32x4 f4 = *(const f32x4*)&fS[r][d];
      zz[r] = fmaf(f4.x, k0, fmaf(f4.y, k1, fmaf(f4.z, k2, fmaf(f4.w, k3, zz[r]))));
    }
  }
  #pragma unroll
  for (int r = 0; r < 16; ++r){
    float v = waveSum(zz[r] * zz[r]);
    if ((t & 63) == 0) red[t >> 6][r] = v;
  }
  __syncthreads();
  #pragma unroll
  for (int r = 0; r < 16; ++r){
    const float ns  = red[0][r] + red[1][r];
    const float nrm = fmaxf(sqrtf(ns), 1e-15f);
    const float th  = tanhf(nrm);
    xh[(size_t)(n0 + r) * Uu + t] = f2bf(zz[r] * (th / nrm));
  }
  if (t < 16){
    const float ns  = red[0][t] + red[1][t];
    const float nrm = fmaxf(sqrtf(ns), 1e-15f);
    const float th  = tanhf(nrm);
    x2[n0 + t] = th * th;
  }
}

// xth[u][n] = xh[n][u] via LDS tiles, coalesced both sides
__global__ __launch_bounds__(256) void k_tr(const short* __restrict__ xh,
                                            short* __restrict__ xth){
  const int n0 = (blockIdx.x & 127) * 64;
  const int u0 = (blockIdx.x >> 7) * 64;
  __shared__ short tS[64][72];
  const int r  = threadIdx.x >> 2;
  const int c0 = (threadIdx.x & 3) * 16;
  const short* src = xh + (size_t)(n0 + r) * Uu + u0 + c0;
  *(s16x8*)&tS[r][c0]     = *(const s16x8*)(src);
  *(s16x8*)&tS[r][c0 + 8] = *(const s16x8*)(src + 8);
  __syncthreads();
  s16x8 b0, b1;
  #pragma unroll
  for (int k = 0; k < 8; ++k){ b0[k] = tS[c0 + k][r]; b1[k] = tS[c0 + 8 + k][r]; }
  short* dst = xth + (size_t)(u0 + r) * Nn + n0 + c0;
  *(s16x8*)(dst)     = b0;
  *(s16x8*)(dst + 8) = b1;
}

__global__ __launch_bounds__(128) void k_bias(const float* __restrict__ bias,
                                              float* __restrict__ bb){
  const int t = threadIdx.x;
  __shared__ float red[2];
  float bv = bias[t];
  float v = waveSum(bv * bv);
  if ((t & 63) == 0) red[t >> 6] = v;
  __syncthreads();
  float n2  = red[0] + red[1];
  float nrm = fmaxf(sqrtf(n2), 1e-15f);
  float th  = tanhf(nrm);
  bb[t] = bv * th / nrm;
  if (t == 0) bb[Uu] = th * th;
}

// Flash window loop, all loads L2-resident (xh 2MB + xth 2MB + x2 + amask 8MB).
// Dist via the Mobius identity num = den * ||xi-xj||^2:
//   d2 = x2i + x2j - 2xy;  den = 1 - 2xy + x2i*x2j;  sq = sqrt(den*d2)
//   p  = (den+sq)/(den-sq) == exp(2*artanh(sqrt(d2/den)))  (shift-0 softmax term)
// NOTE: (256,4); (256,8) forces VGPR<=32 -> 478 MB scratch spill (R7).
__global__ __launch_bounds__(256, 4) void k_attn(const unsigned long long* __restrict__ amask,
                                                 const short* __restrict__ xh,
                                                 const short* __restrict__ xth,
                                                 const float* __restrict__ x2g,
                                                 float* __restrict__ Oacc,
                                                 float* __restrict__ lac){
  const int t    = threadIdx.x;
  const int lane = t & 63;
  const int wid  = t >> 6;
  const int l15  = lane & 15;
  const int q4   = lane >> 4;
  const int i0   = (blockIdx.x >> 1) * MI;
  const int jorg = (blockIdx.x & 1) * JRANGE;
  const int irow = i0 + l15;
  const int mshift = wid * 16 + q4 * 4;

  __shared__ short Pt[2][MI][72];             // 4.5 KB, ping-pong
  __shared__ float oPark[MI][132];            // 8.25 KB, epilogue only

  // Q B-frags in registers for the whole kernel
  s16x8 qf[4];
  {
    const short* qp = xh + (size_t)irow * Uu + q4 * 8;
    #pragma unroll
    for (int kk = 0; kk < 4; ++kk) qf[kk] = *(const s16x8*)(qp + kk * 32);
  }
  const float x2i = x2g[irow];
  const unsigned long long* mrow = amask + (size_t)irow * NMASK + (jorg >> 6);

  f32x4 oac0 = {0.f, 0.f, 0.f, 0.f};
  f32x4 oac1 = {0.f, 0.f, 0.f, 0.f};
  float lacc = 0.f;

#define JSL(w) (jorg + (((w) & (NWIN - 1)) << 6) + (wid << 4))

#define LOADK(S, W) do{                                                        \
    const short* kp_ = xh + (size_t)(JSL(W) + l15) * Uu + q4 * 8;              \
    kf##S[0] = *(const s16x8*)(kp_);                                           \
    kf##S[1] = *(const s16x8*)(kp_ + 32);                                      \
    kf##S[2] = *(const s16x8*)(kp_ + 64);                                      \
    kf##S[3] = *(const s16x8*)(kp_ + 96);                                      \
    xj##S = *(const f32x4*)(x2g + JSL(W) + q4 * 4);                            \
    mk##S = mrow[(W) & (NWIN - 1)];                                            \
  }while(0)

#define PROC(S, W, BUF) do{                                                    \
    const int jw_ = jorg + ((W) << 6);                                         \
    s16x8 vf00_, vf01_, vf10_, vf11_;                                          \
    {                                                                          \
      const short* vp0_ = xth + (size_t)(wid * 32 + l15) * Nn + jw_ + q4 * 8;  \
      const short* vp1_ = vp0_ + 16 * Nn;                                      \
      vf00_ = *(const s16x8*)(vp0_);                                           \
      vf01_ = *(const s16x8*)(vp0_ + 32);                                      \
      vf10_ = *(const s16x8*)(vp1_);                                           \
      vf11_ = *(const s16x8*)(vp1_ + 32);                                      \
    }                                                                          \
    f32x4 s_ = (f32x4){0.f, 0.f, 0.f, 0.f};                                    \
    s_ = MFMA_K32(kf##S[0], qf[0], s_);                                        \
    s_ = MFMA_K32(kf##S[1], qf[1], s_);                                        \
    s_ = MFMA_K32(kf##S[2], qf[2], s_);                                        \
    s_ = MFMA_K32(kf##S[3], qf[3], s_);                                        \
    const unsigned mb_ = (unsigned)(mk##S >> mshift) & 0xFu;                   \
    s16x4 pb_;                                                                 \
    _Pragma("unroll")                                                          \
    for (int r_ = 0; r_ < 4; ++r_){                                            \
      const float xy_  = s_[r_];                                               \
      const float x2j_ = xj##S[r_];                                            \
      const float d2_  = fmaf(-2.f, xy_, x2i + x2j_);                          \
      const float den_ = fmaf(x2i, x2j_, fmaf(-2.f, xy_, 1.f));                \
      const float sq_  = sqrtf(den_ * fmaxf(d2_, 0.f));                        \
      const float pd_  = fmaxf(den_ - sq_, 1e-30f);                            \
      float p_ = fminf((den_ + sq_) * __builtin_amdgcn_rcpf(pd_), 2.0e7f);     \
      const bool keep_ = ((mb_ >> r_) & 1u) && (d2_ > 0.f);                    \
      p_ = keep_ ? p_ : 0.f;                                                   \
      lacc += p_;                                                              \
      pb_[r_] = f2bf(p_);                                                      \
    }                                                                          \
    *(s16x4*)&Pt[BUF][l15][wid * 16 + q4 * 4] = pb_;                           \
    lds_barrier();                                                             \
    {                                                                          \
      const short* pr_ = &Pt[BUF][l15][0];                                     \
      const s16x8 bf0_ = *(const s16x8*)(pr_ + q4 * 8);                        \
      const s16x8 bf1_ = *(const s16x8*)(pr_ + 32 + q4 * 8);                   \
      oac0 = MFMA_K32(vf00_, bf0_, oac0);                                      \
      oac0 = MFMA_K32(vf01_, bf1_, oac0);                                      \
      oac1 = MFMA_K32(vf10_, bf0_, oac1);                                      \
      oac1 = MFMA_K32(vf11_, bf1_, oac1);                                      \
    }                                                                          \
  }while(0)

  s16x8 kfA[4], kfB[4];
  f32x4 xjA, xjB;
  unsigned long long mkA, mkB;
  LOADK(A, 0);
  for (int w = 0; w < NWIN; w += 2){
    LOADK(B, w + 1);
    PROC(A, w, 0);
    LOADK(A, w + 2);                        // wraps to window 0 at the end
    PROC(B, w + 1, 1);
  }
#undef JSL
#undef LOADK
#undef PROC

  // ---- epilogue: l reduce, park O^T -> coalesced atomic add ----
  lacc += __shfl_xor(lacc, 16);
  lacc += __shfl_xor(lacc, 32);
  if (lane < 16) atomicAdd(&lac[i0 + lane], lacc);
  #pragma unroll
  for (int r = 0; r < 4; ++r){
    oPark[l15][wid * 32 + q4 * 4 + r]      = oac0[r];
    oPark[l15][wid * 32 + 16 + q4 * 4 + r] = oac1[r];
  }
  __syncthreads();
  const int er = t >> 4;
  const int ec = t & 15;
  float* dst = Oacc + (size_t)(i0 + er) * Uu + ec * 8;
  #pragma unroll
  for (int k = 0; k < 8; ++k) atomicAdd(dst + k, oPark[er][ec * 8 + k]);
}

// epilogue: normalize, mobius matvec rescale, mobius bias add
__global__ __launch_bounds__(256) void k_out(const float* __restrict__ Oacc,
                                             const float* __restrict__ lac,
                                             const float* __restrict__ x2g,
                                             const float* __restrict__ bb,
                                             float* __restrict__ out){
  const int t  = threadIdx.x;
  const int i0 = blockIdx.x * MI;
  const int er = t >> 4;
  const int ec = t & 15;
  const float linv = 1.f / fmaxf(lac[i0 + er], 1e-30f);
  float mx[8]; float s2 = 0.f;
  #pragma unroll
  for (int k = 0; k < 8; ++k){
    float v = Oacc[(size_t)(i0 + er) * Uu + ec + 16 * k] * linv;
    mx[k] = v; s2 = fmaf(v, v, s2);
  }
  s2 += __shfl_xor(s2, 1); s2 += __shfl_xor(s2, 2);
  s2 += __shfl_xor(s2, 4); s2 += __shfl_xor(s2, 8);
  const float mx_n = fmaxf(sqrtf(s2), 1e-15f);
  const float x2e  = x2g[i0 + er];
  const float x_n  = fmaxf(sqrtf(x2e), 1e-15f);
  const float xcl  = fminf(x_n, 1.f - 1e-7f);
  const float art  = 0.5f * __logf((1.f + xcl) / (1.f - xcl));
  const float th   = tanhf(mx_n / x_n * art);
  const float rmn  = th / mx_n;
  float o[8], bu[8]; float ob = 0.f;
  #pragma unroll
  for (int k = 0; k < 8; ++k){
    bu[k] = bb[ec + 16 * k];
    o[k]  = mx[k] * rmn;
    ob = fmaf(o[k], bu[k], ob);
  }
  ob += __shfl_xor(ob, 1); ob += __shfl_xor(ob, 2);
  ob += __shfl_xor(ob, 4); ob += __shfl_xor(ob, 8);
  const float o2   = th * th;
  const float b2   = bb[Uu];
  const float cnum = 1.f + 2.f * ob + b2;
  const float cden = fmaf(o2, b2, 1.f + 2.f * ob);
  const float rden = 1.f / fmaxf(cden, 1e-15f);
  const float co   = 1.f - o2;
  #pragma unroll
  for (int k = 0; k < 8; ++k)
    out[(size_t)(i0 + er) * Uu + ec + 16 * k] = (cnum * o[k] + co * bu[k]) * rden;
}

extern "C" void kernel_launch(void* const* d_in, const int* in_sizes, int n_in,
                              void* d_out, int out_size, void* d_ws, size_t ws_size,
                              hipStream_t stream){
  (void)in_sizes; (void)n_in; (void)out_size; (void)ws_size;
  const float* feat = (const float*)d_in[0];
  const int*   adj  = (const int*)d_in[1];
  const float* kern = (const float*)d_in[2];
  const float* bias = (const float*)d_in[3];

  short* xh   = (short*)d_ws;                      // [N][U] bf16, 2 MB
  short* xth  = xh + (size_t)Nn * Uu;              // [U][N] bf16, 2 MB
  float* Oacc = (float*)(xth + (size_t)Nn * Uu);   // [N][U] f32, 4 MB
  float* lac  = Oacc + (size_t)Nn * Uu;            // [N]
  float* x2   = lac + Nn;                          // [N]
  float* bbw  = x2 + Nn;                           // [U+1]
  unsigned long long* amask =
      (unsigned long long*)(((uintptr_t)(bbw + Uu + 1) + 15) & ~(uintptr_t)15); // 8 MB

  k_pack<<<2048, 256, 0, stream>>>(adj, amask);
  k_prep<<<Nn / 16, 128, 0, stream>>>(feat, kern, xh, x2, (float4*)Oacc);
  k_tr  <<<256, 256, 0, stream>>>(xh, xth);
  k_bias<<<1, 128, 0, stream>>>(bias, bbw);
  k_attn<<<(Nn / MI) * JS, 256, 0, stream>>>(amask, xh, xth, x2, Oacc, lac);
  k_out <<<Nn / MI, 256, 0, stream>>>(Oacc, lac, x2, bbw, (float*)d_out);
}